// Round 1
// baseline (528.338 us; speedup 1.0000x reference)
//
#include <hip/hip_runtime.h>

#define B_ 16
#define C_ 512
#define S_ 4096

typedef __attribute__((ext_vector_type(4))) float float4v;
typedef __attribute__((ext_vector_type(8))) short short8;
typedef __attribute__((ext_vector_type(4))) short short4v;

typedef __attribute__((address_space(1))) unsigned int as1_uint;
typedef __attribute__((address_space(3))) unsigned int as3_uint;

// async global->LDS, 16 bytes per lane (emits global_load_lds_dwordx4)
#define ASYNC16(gsrc, ldst) \
  __builtin_amdgcn_global_load_lds((as1_uint*)(gsrc), (as3_uint*)(ldst), 16, 0, 0)

__device__ __forceinline__ unsigned short f2bf(float f) {
  unsigned u = __builtin_bit_cast(unsigned, f);
  u = u + 0x7FFFu + ((u >> 16) & 1u);  // round-to-nearest-even
  return (unsigned short)(u >> 16);
}

// ---------------- kernel 1: depthT[b][s][d] = bf16(depth[b][d][s]) -------------
__global__ __launch_bounds__(256) void k_transpose(
    const float* __restrict__ depth, unsigned short* __restrict__ depthT) {
  __shared__ float tile[32][33];
  int b = blockIdx.z;
  int s0 = blockIdx.x * 32, d0 = blockIdx.y * 32;
  int tx = threadIdx.x & 31, ty = threadIdx.x >> 5;  // ty in 0..7
  const float* src = depth + (b * C_ + d0) * S_ + s0;
#pragma unroll
  for (int p = 0; p < 4; ++p) {
    int d = ty + p * 8;
    tile[d][tx] = src[d * S_ + tx];  // coalesced along s
  }
  __syncthreads();
  unsigned short* dst = depthT + (b * S_ + s0) * C_ + d0;
#pragma unroll
  for (int p = 0; p < 4; ++p) {
    int s = ty + p * 8;
    dst[s * C_ + tx] = f2bf(tile[tx][s]);  // coalesced along d; LDS stride 33 = conflict-free
  }
}

// ---------------- kernel 2: I[b][c][d] = bf16(sigmoid(sum_s depth[c,s]*rgb[d,s])) ----
// fp32 inputs, manual staging (load->cvt bf16->LDS), padded LDS, reg-prefetch pipeline.
__global__ __launch_bounds__(256) void k_gemm1(
    const float* __restrict__ depth, const float* __restrict__ rgb,
    unsigned short* __restrict__ I) {
  const int BK = 32, LDA = 40;  // pad 32->40 shorts: 80B row stride -> <=2-way bank conflicts
  __shared__ __align__(16) short As[128 * LDA];
  __shared__ __align__(16) short Bs[128 * LDA];
  int b = blockIdx.z;
  int c0 = blockIdx.x * 128, d0 = blockIdx.y * 128;
  int t = threadIdx.x;
  const float* Abase = depth + (b * C_ + c0) * S_;
  const float* Bbase = rgb + (b * C_ + d0) * S_;
  int w = t >> 6, l = t & 63, half = l >> 4, r = l & 15;
  int wm = (w >> 1) * 64, wn = (w & 1) * 64;

  float4v acc[4][4] = {};
  float4v pa[4], pb[4];

  // prologue: prefetch tile k=0 into registers
#pragma unroll
  for (int q = 0; q < 4; ++q) {
    int idx = q * 256 + t, row = idx >> 3, ch = idx & 7;
    pa[q] = *(const float4v*)(Abase + row * S_ + ch * 4);
    pb[q] = *(const float4v*)(Bbase + row * S_ + ch * 4);
  }

  for (int kt = 0; kt < S_ / BK; ++kt) {
    // convert prefetched regs to bf16, stage to LDS
#pragma unroll
    for (int q = 0; q < 4; ++q) {
      int idx = q * 256 + t, row = idx >> 3, ch = idx & 7;
      short4v sa = {(short)f2bf(pa[q].x), (short)f2bf(pa[q].y),
                    (short)f2bf(pa[q].z), (short)f2bf(pa[q].w)};
      short4v sb = {(short)f2bf(pb[q].x), (short)f2bf(pb[q].y),
                    (short)f2bf(pb[q].z), (short)f2bf(pb[q].w)};
      *(short4v*)&As[row * LDA + ch * 4] = sa;
      *(short4v*)&Bs[row * LDA + ch * 4] = sb;
    }
    __syncthreads();
    // issue next tile's global loads early; MFMA below hides their latency
    if (kt + 1 < S_ / BK) {
      int k0 = (kt + 1) * BK;
#pragma unroll
      for (int q = 0; q < 4; ++q) {
        int idx = q * 256 + t, row = idx >> 3, ch = idx & 7;
        pa[q] = *(const float4v*)(Abase + row * S_ + k0 + ch * 4);
        pb[q] = *(const float4v*)(Bbase + row * S_ + k0 + ch * 4);
      }
    }
    short8 af[4], bfr[4];
#pragma unroll
    for (int i = 0; i < 4; ++i)
      af[i] = *(const short8*)&As[(wm + 16 * i + r) * LDA + half * 8];
#pragma unroll
    for (int j = 0; j < 4; ++j)
      bfr[j] = *(const short8*)&Bs[(wn + 16 * j + r) * LDA + half * 8];
#pragma unroll
    for (int i = 0; i < 4; ++i)
#pragma unroll
      for (int j = 0; j < 4; ++j)
        acc[i][j] =
            __builtin_amdgcn_mfma_f32_16x16x32_bf16(af[i], bfr[j], acc[i][j], 0, 0, 0);
    __syncthreads();
  }

  // epilogue: sigmoid -> bf16 store.  C/D layout: col=lane&15, row=(lane>>4)*4+reg
#pragma unroll
  for (int i = 0; i < 4; ++i)
#pragma unroll
    for (int j = 0; j < 4; ++j)
#pragma unroll
      for (int reg = 0; reg < 4; ++reg) {
        int c = c0 + wm + 16 * i + half * 4 + reg;
        int d = d0 + wn + 16 * j + r;
        float x = acc[i][j][reg];
        float sg = 1.0f / (1.0f + __expf(-x));
        I[(b * C_ + c) * C_ + d] = f2bf(sg);
      }
}

// ---------------- kernel 3: out[b][c][s] = rgb[b][c][s] + sum_d I[c,d]*depthT[s,d] ----
// clean bf16 NT GEMM, m97 structure with global_load_lds width 16.
__global__ __launch_bounds__(256) void k_gemm2(
    const unsigned short* __restrict__ I, const unsigned short* __restrict__ depthT,
    const float* __restrict__ rgb, float* __restrict__ out) {
  const int BK = 32;
  __shared__ __align__(16) short As[128 * BK];  // 8 KB, contiguous (global_load_lds order)
  __shared__ __align__(16) short Bs[128 * BK];  // 8 KB
  int b = blockIdx.z;
  int c0 = blockIdx.x * 128, s0 = blockIdx.y * 128;
  int t = threadIdx.x;
  const unsigned short* Ab = I + (b * C_ + c0) * C_;
  const unsigned short* Bb = depthT + (b * S_ + s0) * C_;
  int w = t >> 6, l = t & 63, half = l >> 4, r = l & 15;
  int wm = (w >> 1) * 64, wn = (w & 1) * 64;
  float4v acc[4][4] = {};

  for (int k0 = 0; k0 < C_; k0 += BK) {
    __syncthreads();  // prior iter's LDS reads done before overwrite
#pragma unroll
    for (int q = 0; q < 2; ++q) {
      int idx = q * 256 + t;  // row = idx>>2 (32 bf16 = 4 chunks of 16B), chunk = idx&3
      ASYNC16(Ab + (idx >> 2) * C_ + k0 + (idx & 3) * 8, &As[idx * 8]);
    }
#pragma unroll
    for (int q = 0; q < 2; ++q) {
      int idx = q * 256 + t;
      ASYNC16(Bb + (idx >> 2) * C_ + k0 + (idx & 3) * 8, &Bs[idx * 8]);
    }
    __syncthreads();  // emits s_waitcnt vmcnt(0) -> LDS tiles valid

    short8 af[4], bfr[4];
#pragma unroll
    for (int i = 0; i < 4; ++i)
      af[i] = *(const short8*)&As[(wm + 16 * i + r) * BK + half * 8];
#pragma unroll
    for (int j = 0; j < 4; ++j)
      bfr[j] = *(const short8*)&Bs[(wn + 16 * j + r) * BK + half * 8];
#pragma unroll
    for (int i = 0; i < 4; ++i)
#pragma unroll
      for (int j = 0; j < 4; ++j)
        acc[i][j] =
            __builtin_amdgcn_mfma_f32_16x16x32_bf16(af[i], bfr[j], acc[i][j], 0, 0, 0);
  }

  // epilogue: fused = rgb + acc
#pragma unroll
  for (int i = 0; i < 4; ++i)
#pragma unroll
    for (int j = 0; j < 4; ++j)
#pragma unroll
      for (int reg = 0; reg < 4; ++reg) {
        int c = c0 + wm + 16 * i + half * 4 + reg;
        int s = s0 + wn + 16 * j + r;
        int o = (b * C_ + c) * S_ + s;
        out[o] = rgb[o] + acc[i][j][reg];
      }
}

extern "C" void kernel_launch(void* const* d_in, const int* in_sizes, int n_in,
                              void* d_out, int out_size, void* d_ws, size_t ws_size,
                              hipStream_t stream) {
  const float* rgb = (const float*)d_in[0];    // rgb_feat
  const float* depth = (const float*)d_in[1];  // depth_feat
  float* out = (float*)d_out;
  // workspace layout: depthT bf16 (64 MiB) | I bf16 (8 MiB)  => 75.5 MB total
  unsigned short* depthT = (unsigned short*)d_ws;
  unsigned short* I = (unsigned short*)((char*)d_ws + (size_t)B_ * S_ * C_ * 2);

  k_transpose<<<dim3(S_ / 32, C_ / 32, B_), 256, 0, stream>>>(depth, depthT);
  k_gemm1<<<dim3(C_ / 128, C_ / 128, B_), 256, 0, stream>>>(depth, rgb, I);
  k_gemm2<<<dim3(C_ / 128, S_ / 128, B_), 256, 0, stream>>>(I, depthT, rgb, out);
}

// Round 2
// 492.769 us; speedup vs baseline: 1.0722x; 1.0722x over previous
//
#include <hip/hip_runtime.h>

#define B_ 16
#define C_ 512
#define S_ 4096

typedef __attribute__((ext_vector_type(4))) float float4v;
typedef __attribute__((ext_vector_type(8))) short short8;
typedef __attribute__((ext_vector_type(4))) short short4v;

typedef __attribute__((address_space(1))) unsigned int as1_uint;
typedef __attribute__((address_space(3))) unsigned int as3_uint;

// async global->LDS, 16 bytes per lane (emits global_load_lds_dwordx4)
#define ASYNC16(gsrc, ldst) \
  __builtin_amdgcn_global_load_lds((as1_uint*)(gsrc), (as3_uint*)(ldst), 16, 0, 0)

__device__ __forceinline__ unsigned short f2bf(float f) {
  unsigned u = __builtin_bit_cast(unsigned, f);
  u = u + 0x7FFFu + ((u >> 16) & 1u);  // round-to-nearest-even
  return (unsigned short)(u >> 16);
}

// ---------------- kernel 1: depthT[b][s][d] = bf16(depth[b][d][s]) -------------
// 64(s) x 128(d) tile; float4 loads, ushort4 stores (256B per 32-lane group).
__global__ __launch_bounds__(256) void k_transpose(
    const float* __restrict__ depth, unsigned short* __restrict__ depthT) {
  __shared__ float tile[64][129];  // [s][d]; stride 129 -> load scatter is 2-way (free)
  int b = blockIdx.z;
  int s0 = blockIdx.x * 64, d0 = blockIdx.y * 128;
  int t = threadIdx.x;
  const float* src = depth + (b * C_ + d0) * S_ + s0;
#pragma unroll
  for (int it = 0; it < 8; ++it) {
    int slot = it * 256 + t;
    int d = slot >> 4, l16 = slot & 15;  // 16 lanes cover 64 s as float4
    float4v v = *(const float4v*)(src + d * S_ + l16 * 4);
    tile[l16 * 4 + 0][d] = v.x;
    tile[l16 * 4 + 1][d] = v.y;
    tile[l16 * 4 + 2][d] = v.z;
    tile[l16 * 4 + 3][d] = v.w;
  }
  __syncthreads();
  unsigned short* dst = depthT + (b * S_ + s0) * C_ + d0;
#pragma unroll
  for (int it = 0; it < 8; ++it) {
    int slot = it * 256 + t;
    int s = slot >> 5, l32 = slot & 31;  // 32 lanes cover 128 d as ushort4
    float x0 = tile[s][l32 * 4 + 0];
    float x1 = tile[s][l32 * 4 + 1];
    float x2 = tile[s][l32 * 4 + 2];
    float x3 = tile[s][l32 * 4 + 3];
    short4v o = {(short)f2bf(x0), (short)f2bf(x1), (short)f2bf(x2), (short)f2bf(x3)};
    *(short4v*)(dst + s * C_ + l32 * 4) = o;  // 8 B/lane coalesced
  }
}

// ---------------- kernel 2: split-K=4 partial GEMM1 ---------------------------
// partial[ks][b][c][d] = sum_{s in ks-chunk} depth[c,s]*rgb[d,s]  (fp32, into d_out)
__global__ __launch_bounds__(256) void k_gemm1(
    const float* __restrict__ depth, const float* __restrict__ rgb,
    float* __restrict__ partial) {
  const int BK = 32, LDA = 40;  // pad 32->40 shorts: <=2-way bank conflicts
  __shared__ __align__(16) short As[128 * LDA];
  __shared__ __align__(16) short Bs[128 * LDA];
  int bz = blockIdx.z;
  int b = bz >> 2, ks = bz & 3;        // split-K chunk of 1024
  int c0 = blockIdx.x * 128, d0 = blockIdx.y * 128;
  int t = threadIdx.x;
  const float* Abase = depth + (size_t)(b * C_ + c0) * S_ + ks * 1024;
  const float* Bbase = rgb + (size_t)(b * C_ + d0) * S_ + ks * 1024;
  int w = t >> 6, l = t & 63, half = l >> 4, r = l & 15;
  int wm = (w >> 1) * 64, wn = (w & 1) * 64;

  float4v acc[4][4] = {};
  float4v pa[4], pb[4];

  // prologue: prefetch tile k=0 into registers
#pragma unroll
  for (int q = 0; q < 4; ++q) {
    int idx = q * 256 + t, row = idx >> 3, ch = idx & 7;
    pa[q] = *(const float4v*)(Abase + row * S_ + ch * 4);
    pb[q] = *(const float4v*)(Bbase + row * S_ + ch * 4);
  }

  const int NKT = 1024 / BK;  // 32
  for (int kt = 0; kt < NKT; ++kt) {
#pragma unroll
    for (int q = 0; q < 4; ++q) {
      int idx = q * 256 + t, row = idx >> 3, ch = idx & 7;
      short4v sa = {(short)f2bf(pa[q].x), (short)f2bf(pa[q].y),
                    (short)f2bf(pa[q].z), (short)f2bf(pa[q].w)};
      short4v sb = {(short)f2bf(pb[q].x), (short)f2bf(pb[q].y),
                    (short)f2bf(pb[q].z), (short)f2bf(pb[q].w)};
      *(short4v*)&As[row * LDA + ch * 4] = sa;
      *(short4v*)&Bs[row * LDA + ch * 4] = sb;
    }
    __syncthreads();
    if (kt + 1 < NKT) {
      int k0 = (kt + 1) * BK;
#pragma unroll
      for (int q = 0; q < 4; ++q) {
        int idx = q * 256 + t, row = idx >> 3, ch = idx & 7;
        pa[q] = *(const float4v*)(Abase + row * S_ + k0 + ch * 4);
        pb[q] = *(const float4v*)(Bbase + row * S_ + k0 + ch * 4);
      }
    }
    short8 af[4], bfr[4];
#pragma unroll
    for (int i = 0; i < 4; ++i)
      af[i] = *(const short8*)&As[(wm + 16 * i + r) * LDA + half * 8];
#pragma unroll
    for (int j = 0; j < 4; ++j)
      bfr[j] = *(const short8*)&Bs[(wn + 16 * j + r) * LDA + half * 8];
#pragma unroll
    for (int i = 0; i < 4; ++i)
#pragma unroll
      for (int j = 0; j < 4; ++j)
        acc[i][j] =
            __builtin_amdgcn_mfma_f32_16x16x32_bf16(af[i], bfr[j], acc[i][j], 0, 0, 0);
    __syncthreads();
  }

  // store fp32 partials (no sigmoid yet). C/D layout: col=lane&15, row=(lane>>4)*4+reg
  float* P = partial + ((size_t)(ks * B_ + b) * C_) * C_;
#pragma unroll
  for (int i = 0; i < 4; ++i)
#pragma unroll
    for (int j = 0; j < 4; ++j)
#pragma unroll
      for (int reg = 0; reg < 4; ++reg) {
        int c = c0 + wm + 16 * i + half * 4 + reg;
        int d = d0 + wn + 16 * j + r;
        P[(size_t)c * C_ + d] = acc[i][j][reg];
      }
}

// ---------------- kernel 2b: reduce 4 partials + sigmoid -> I bf16 -------------
__global__ __launch_bounds__(256) void k_reduce(const float* __restrict__ p,
                                                unsigned short* __restrict__ I) {
  const size_t n = (size_t)B_ * C_ * C_;
  size_t idx = ((size_t)blockIdx.x * 256 + threadIdx.x) * 4;
  float4v s = *(const float4v*)(p + idx);
  s += *(const float4v*)(p + n + idx);
  s += *(const float4v*)(p + 2 * n + idx);
  s += *(const float4v*)(p + 3 * n + idx);
  float g0 = 1.0f / (1.0f + __expf(-s.x));
  float g1 = 1.0f / (1.0f + __expf(-s.y));
  float g2 = 1.0f / (1.0f + __expf(-s.z));
  float g3 = 1.0f / (1.0f + __expf(-s.w));
  short4v o = {(short)f2bf(g0), (short)f2bf(g1), (short)f2bf(g2), (short)f2bf(g3)};
  *(short4v*)(I + idx) = o;
}

// ---------------- kernel 3: out[b][c][s] = rgb[b][c][s] + sum_d I[c,d]*depthT[s,d] ----
__global__ __launch_bounds__(256) void k_gemm2(
    const unsigned short* __restrict__ I, const unsigned short* __restrict__ depthT,
    const float* __restrict__ rgb, float* __restrict__ out) {
  const int BK = 32;
  __shared__ __align__(16) short As[128 * BK];
  __shared__ __align__(16) short Bs[128 * BK];
  int b = blockIdx.z;
  int c0 = blockIdx.x * 128, s0 = blockIdx.y * 128;
  int t = threadIdx.x;
  const unsigned short* Ab = I + (size_t)(b * C_ + c0) * C_;
  const unsigned short* Bb = depthT + (size_t)(b * S_ + s0) * C_;
  int w = t >> 6, l = t & 63, half = l >> 4, r = l & 15;
  int wm = (w >> 1) * 64, wn = (w & 1) * 64;
  float4v acc[4][4] = {};

  for (int k0 = 0; k0 < C_; k0 += BK) {
    __syncthreads();
#pragma unroll
    for (int q = 0; q < 2; ++q) {
      int idx = q * 256 + t;
      ASYNC16(Ab + (idx >> 2) * C_ + k0 + (idx & 3) * 8, &As[idx * 8]);
    }
#pragma unroll
    for (int q = 0; q < 2; ++q) {
      int idx = q * 256 + t;
      ASYNC16(Bb + (idx >> 2) * C_ + k0 + (idx & 3) * 8, &Bs[idx * 8]);
    }
    __syncthreads();

    short8 af[4], bfr[4];
#pragma unroll
    for (int i = 0; i < 4; ++i)
      af[i] = *(const short8*)&As[(wm + 16 * i + r) * BK + half * 8];
#pragma unroll
    for (int j = 0; j < 4; ++j)
      bfr[j] = *(const short8*)&Bs[(wn + 16 * j + r) * BK + half * 8];
#pragma unroll
    for (int i = 0; i < 4; ++i)
#pragma unroll
      for (int j = 0; j < 4; ++j)
        acc[i][j] =
            __builtin_amdgcn_mfma_f32_16x16x32_bf16(af[i], bfr[j], acc[i][j], 0, 0, 0);
  }

#pragma unroll
  for (int i = 0; i < 4; ++i)
#pragma unroll
    for (int j = 0; j < 4; ++j)
#pragma unroll
      for (int reg = 0; reg < 4; ++reg) {
        int c = c0 + wm + 16 * i + half * 4 + reg;
        int s = s0 + wn + 16 * j + r;
        size_t o = (size_t)(b * C_ + c) * S_ + s;
        out[o] = rgb[o] + acc[i][j][reg];
      }
}

extern "C" void kernel_launch(void* const* d_in, const int* in_sizes, int n_in,
                              void* d_out, int out_size, void* d_ws, size_t ws_size,
                              hipStream_t stream) {
  const float* rgb = (const float*)d_in[0];    // rgb_feat
  const float* depth = (const float*)d_in[1];  // depth_feat
  float* out = (float*)d_out;
  // ws layout: depthT bf16 (64 MiB) | I bf16 (8 MiB)
  unsigned short* depthT = (unsigned short*)d_ws;
  unsigned short* I = (unsigned short*)((char*)d_ws + (size_t)B_ * S_ * C_ * 2);
  // split-K partials (4 x 16 MiB fp32) live in d_out, consumed by k_reduce
  // before k_gemm2 overwrites d_out with the final result.
  float* partial = out;

  k_transpose<<<dim3(S_ / 64, C_ / 128, B_), 256, 0, stream>>>(depth, depthT);
  k_gemm1<<<dim3(C_ / 128, C_ / 128, B_ * 4), 256, 0, stream>>>(depth, rgb, partial);
  k_reduce<<<dim3((B_ * C_ * C_) / 1024), 256, 0, stream>>>(partial, I);
  k_gemm2<<<dim3(C_ / 128, S_ / 128, B_), 256, 0, stream>>>(I, depthT, rgb, out);
}